// Round 5
// baseline (4390.531 us; speedup 1.0000x reference)
//
#include <hip/hip_runtime.h>
#include <cstdint>
#include <cstddef>

#define S_LEN 2048
#define BATCH 64
#define ISZ   256
#define HSZ   128

// ---------------------------------------------------------------------------
// GEMM: C = A(MxK) @ W(NxK)^T (+bias)
// LAYOUT 0: C[m*N + n]   (row-major M x N)
// LAYOUT 1: C[(m/64)*N*64 + n*64 + (m%64)]   -> (s, c, b) transposed store
// ---------------------------------------------------------------------------
template<int LAYOUT>
__global__ __launch_bounds__(256)
void gemm_nt(const float* __restrict__ A, const float* __restrict__ W,
             const float* __restrict__ bias, float* __restrict__ C,
             int M, int N, int K)
{
    __shared__ float As[64][65];   // pad 65: A-reads 2-way conflict max
    __shared__ float Bs[64][68];   // pad 68: float4-aligned reads along n
    const int tid = threadIdx.x;
    const int tc = tid & 15, tr = tid >> 4;
    const int m0 = blockIdx.y * 64;
    const int n0 = blockIdx.x * 64;

    float acc[4][4] = {};

    for (int k0 = 0; k0 < K; k0 += 64) {
        // stage A tile (64 rows x 64 k), coalesced float4
        #pragma unroll
        for (int it = 0; it < 4; ++it) {
            int idx = tid + it * 256;
            int r = idx >> 4, c4 = (idx & 15) * 4;
            const float4 v = *reinterpret_cast<const float4*>(
                &A[(size_t)(m0 + r) * K + k0 + c4]);
            As[r][c4+0] = v.x; As[r][c4+1] = v.y;
            As[r][c4+2] = v.z; As[r][c4+3] = v.w;
        }
        // stage W tile transposed: Bs[k][n] = W[n0+n][k0+k]
        #pragma unroll
        for (int it = 0; it < 4; ++it) {
            int idx = tid + it * 256;
            int n = idx >> 4, k4 = (idx & 15) * 4;
            const float4 v = *reinterpret_cast<const float4*>(
                &W[(size_t)(n0 + n) * K + k0 + k4]);
            Bs[k4+0][n] = v.x; Bs[k4+1][n] = v.y;
            Bs[k4+2][n] = v.z; Bs[k4+3][n] = v.w;
        }
        __syncthreads();

        #pragma unroll
        for (int kk = 0; kk < 64; ++kk) {
            float a0 = As[tr*4+0][kk];
            float a1 = As[tr*4+1][kk];
            float a2 = As[tr*4+2][kk];
            float a3 = As[tr*4+3][kk];
            float4 b = *reinterpret_cast<const float4*>(&Bs[kk][tc*4]);
            acc[0][0] += a0*b.x; acc[0][1] += a0*b.y; acc[0][2] += a0*b.z; acc[0][3] += a0*b.w;
            acc[1][0] += a1*b.x; acc[1][1] += a1*b.y; acc[1][2] += a1*b.z; acc[1][3] += a1*b.w;
            acc[2][0] += a2*b.x; acc[2][1] += a2*b.y; acc[2][2] += a2*b.z; acc[2][3] += a2*b.w;
            acc[3][0] += a3*b.x; acc[3][1] += a3*b.y; acc[3][2] += a3*b.z; acc[3][3] += a3*b.w;
        }
        __syncthreads();
    }

    float bv[4];
    #pragma unroll
    for (int j = 0; j < 4; ++j)
        bv[j] = bias ? bias[n0 + tc*4 + j] : 0.f;

    #pragma unroll
    for (int i = 0; i < 4; ++i) {
        #pragma unroll
        for (int j = 0; j < 4; ++j) {
            float v = acc[i][j] + bv[j];
            int m = m0 + tr*4 + i;
            int n = n0 + tc*4 + j;
            if (LAYOUT == 0)
                C[(size_t)m * N + n] = v;
            else
                C[(size_t)(m >> 6) * ((size_t)N * 64) + (size_t)n * 64 + (m & 63)] = v;
        }
    }
}

// ---------------------------------------------------------------------------
// GRU recurrence: one WG per (direction, batch), 384 threads = 6 waves.
// Thread j owns gate row j: 128 weight words in VGPRs.  h is wave-uniform:
// each wave keeps h in 2 per-lane registers (hv0,hv1) and broadcasts via
// v_readlane -> SGPR, so the matvec has ZERO LDS traffic.
// KEY (round-4 lesson): __launch_bounds__ second arg MUST be 1.  At min-2-
// waves/EU the 256-VGPR cap makes the allocator dump w[128] to scratch
// (r4: VGPR_Count=76, 2.6ms); at (256,1)/cap-512 a 128-word array stays
// resident (r3: 208).  Occupancy is irrelevant here: only 128 WGs exist,
// 1 WG/CU covers them; the kernel is critical-path latency-bound.
// ---------------------------------------------------------------------------
#define RL(v, l) __int_as_float(__builtin_amdgcn_readlane(__float_as_int(v), (l)))

__global__ __launch_bounds__(384, 1)
void gru_scan(const float* __restrict__ xg_f, const float* __restrict__ xg_b,
              const float* __restrict__ whh_f, const float* __restrict__ whh_b,
              const float* __restrict__ bhh_f, const float* __restrict__ bhh_b,
              const float* __restrict__ h0,     // (2,64,128)
              float* __restrict__ outs,         // (S,64,256)
              float* __restrict__ hid_out)      // (2,64,128)
{
    const int j    = threadIdx.x;        // 0..383, owns gate row j
    const int lane = j & 63;
    const int dir  = blockIdx.x >> 6;
    const int b    = blockIdx.x & 63;
    const bool low = (j < 128);          // wave-uniform

    const float* xg  = dir ? xg_b  : xg_f;
    const float* whh = dir ? whh_b : whh_f;
    const float* bhh = dir ? bhh_b : bhh_f;

    float w[128];
    #pragma unroll
    for (int k4 = 0; k4 < 32; ++k4) {
        float4 v = *reinterpret_cast<const float4*>(&whh[(size_t)j * 128 + k4 * 4]);
        asm volatile("" : "+v"(v.x), "+v"(v.y), "+v"(v.z), "+v"(v.w));
        w[k4*4+0] = v.x; w[k4*4+1] = v.y; w[k4*4+2] = v.z; w[k4*4+3] = v.w;
    }
    const float bh = bhh[j];

    __shared__ float hs[128];
    __shared__ float ghs[384];   // only 128..383 used

    float hj = 0.f, xr = 0.f, xz = 0.f, xn = 0.f;
    if (low) {
        hj = h0[dir * (64*128) + b * 128 + j];
        hs[j] = hj;
        const int s0 = dir ? (S_LEN - 1) : 0;
        const float* xrow = xg + ((size_t)s0 * 64 + b) * 384;
        xr = xrow[j]; xz = xrow[j + 128]; xn = xrow[j + 256];
    }
    asm volatile("s_waitcnt lgkmcnt(0)" ::: "memory");
    __builtin_amdgcn_s_barrier();

    for (int t = 0; t < S_LEN; ++t) {
        // wave-local h copy: the ONLY LDS reads feeding the matvec
        // (lane l holds h[l] in hv0, h[64+l] in hv1; 2-way bank alias = free)
        const float hv0 = hs[lane];
        const float hv1 = hs[64 + lane];

        // x(t+1) prefetch: a full step of slack, vmcnt never drained
        float pxr = 0.f, pxz = 0.f, pxn = 0.f;
        if (low && t + 1 < S_LEN) {
            const int s1 = dir ? (S_LEN - 2 - t) : (t + 1);
            const float* xrow = xg + ((size_t)s1 * 64 + b) * 384;
            pxr = xrow[j]; pxz = xrow[j + 128]; pxn = xrow[j + 256];
        }

        // matvec row j: 128 readlane broadcasts + 128 FMA, 4-way acc split
        float a0 = 0.f, a1 = 0.f, a2 = 0.f, a3 = 0.f;
        #pragma unroll
        for (int k = 0; k < 64; k += 4) {
            a0 = fmaf(w[k+0], RL(hv0, k+0), a0);
            a1 = fmaf(w[k+1], RL(hv0, k+1), a1);
            a2 = fmaf(w[k+2], RL(hv0, k+2), a2);
            a3 = fmaf(w[k+3], RL(hv0, k+3), a3);
        }
        #pragma unroll
        for (int k = 0; k < 64; k += 4) {
            a0 = fmaf(w[64+k+0], RL(hv1, k+0), a0);
            a1 = fmaf(w[64+k+1], RL(hv1, k+1), a1);
            a2 = fmaf(w[64+k+2], RL(hv1, k+2), a2);
            a3 = fmaf(w[64+k+3], RL(hv1, k+3), a3);
        }
        const float g = (a0 + a1) + (a2 + a3) + bh;
        if (!low) ghs[j] = g;            // z/n rows publish; r row keeps local

        asm volatile("s_waitcnt lgkmcnt(0)" ::: "memory");
        __builtin_amdgcn_s_barrier();

        if (low) {
            const float hr = g;
            const float hz = ghs[j + 128];
            const float hn = ghs[j + 256];
            const float r = 1.f / (1.f + __expf(-(xr + hr)));
            const float z = 1.f / (1.f + __expf(-(xz + hz)));
            const float x2 = xn + r * hn;
            const float ax = fabsf(x2);
            const float e  = __expf(-2.f * ax);
            const float nn = copysignf((1.f - e) / (1.f + e), x2);  // tanh
            const float hnew = nn + z * (hj - nn);   // (1-z)*n + z*h
            hj = hnew;
            hs[j] = hnew;
            const int s = dir ? (S_LEN - 1 - t) : t;
            outs[((size_t)s * 64 + b) * 256 + dir * 128 + j] = hnew;
            xr = pxr; xz = pxz; xn = pxn;
        }

        asm volatile("s_waitcnt lgkmcnt(0)" ::: "memory");
        __builtin_amdgcn_s_barrier();
    }

    if (low) hid_out[dir * (64*128) + b * 128 + j] = hj;
}

// ---------------------------------------------------------------------------
// Batch-axis softmax (over b, 64 lanes = one wave) + weighted partial
// reduction over a 32-step s-chunk.  logits are in (S, C, B) layout.
// ---------------------------------------------------------------------------
__global__ __launch_bounds__(256)
void attn_reduce(const float* __restrict__ lt,    // (S,256,64)
                 const float* __restrict__ outs,  // (S,64,256)
                 float* __restrict__ part)        // (64 chunks,64 b,256 c)
{
    __shared__ float ltile[64 * 64];     // [c_local][b]
    __shared__ float otile[64 * 65];     // [b][c_local] padded

    const int tid  = threadIdx.x;
    const int lane = tid & 63;           // = b
    const int wv   = tid >> 6;           // wave 0..3
    const int c0   = blockIdx.x * 64;    // channel block
    const int sc   = blockIdx.y;         // s-chunk 0..63

    float acc[16];
    #pragma unroll
    for (int i = 0; i < 16; ++i) acc[i] = 0.f;

    for (int si = 0; si < 32; ++si) {
        const int s = sc * 32 + si;

        // logits tile: 4096 contiguous floats
        const float4* src = reinterpret_cast<const float4*>(
            lt + (size_t)s * 16384 + (size_t)c0 * 64);
        #pragma unroll
        for (int i = 0; i < 4; ++i)
            reinterpret_cast<float4*>(ltile)[tid + i * 256] = src[tid + i * 256];

        // out_state tile (64 b x 64 c), coalesced along c
        #pragma unroll
        for (int i = 0; i < 4; ++i) {
            int idx = tid + i * 256;
            int bb = idx >> 4, c4 = (idx & 15) * 4;
            float4 v = *reinterpret_cast<const float4*>(
                &outs[((size_t)s * 64 + bb) * 256 + c0 + c4]);
            otile[bb*65 + c4+0] = v.x; otile[bb*65 + c4+1] = v.y;
            otile[bb*65 + c4+2] = v.z; otile[bb*65 + c4+3] = v.w;
        }
        __syncthreads();

        #pragma unroll
        for (int ci = 0; ci < 16; ++ci) {
            int c = wv * 16 + ci;
            float x = ltile[c * 64 + lane];
            float m = x;
            #pragma unroll
            for (int off = 32; off; off >>= 1)
                m = fmaxf(m, __shfl_xor(m, off));
            float e = __expf(x - m);
            float ssum = e;
            #pragma unroll
            for (int off = 32; off; off >>= 1)
                ssum += __shfl_xor(ssum, off);
            float attn = e / ssum;
            acc[ci] += attn * otile[lane * 65 + c];
        }
        __syncthreads();
    }

    #pragma unroll
    for (int ci = 0; ci < 16; ++ci) {
        int c = wv * 16 + ci;
        part[(size_t)sc * 16384 + (size_t)lane * 256 + c0 + c] = acc[ci];
    }
}

__global__ __launch_bounds__(256)
void reduce_part(const float* __restrict__ part, float* __restrict__ sent)
{
    int idx = blockIdx.x * 256 + threadIdx.x;   // 0..16383 = b*256+c
    float s = 0.f;
    for (int sc = 0; sc < 64; ++sc)
        s += part[(size_t)sc * 16384 + idx];
    sent[idx] = s;
}

// ---------------------------------------------------------------------------
extern "C" void kernel_launch(void* const* d_in, const int* in_sizes, int n_in,
                              void* d_out, int out_size, void* d_ws, size_t ws_size,
                              hipStream_t stream)
{
    const float* inp    = (const float*)d_in[0];
    const float* hid0   = (const float*)d_in[1];
    const float* w_ih_f = (const float*)d_in[2];
    const float* w_hh_f = (const float*)d_in[3];
    const float* b_ih_f = (const float*)d_in[4];
    const float* b_hh_f = (const float*)d_in[5];
    const float* w_ih_b = (const float*)d_in[6];
    const float* w_hh_b = (const float*)d_in[7];
    const float* b_ih_b = (const float*)d_in[8];
    const float* b_hh_b = (const float*)d_in[9];
    const float* attn_w = (const float*)d_in[10];
    const float* attn_b = (const float*)d_in[11];
    const float* comb_w = (const float*)d_in[12];

    float* out = (float*)d_out;   // [0,16384): sent, [16384,32768): hid_out

    char* ws = (char*)d_ws;
    const size_t XG_BYTES = (size_t)S_LEN * BATCH * 384 * 4;  // 201,326,592
    const size_t OS_BYTES = (size_t)S_LEN * BATCH * 256 * 4;  // 134,217,728
    if (ws_size < 2 * XG_BYTES + OS_BYTES) return;  // need 512 MiB scratch

    float* xg_f   = (float*)(ws);
    float* xg_b   = (float*)(ws + XG_BYTES);
    float* outs   = (float*)(ws + 2 * XG_BYTES);
    float* sa     = (float*)(ws);               // reuse xg_f (dead after scan)
    float* logits = (float*)(ws + XG_BYTES);    // reuse xg_b
    float* part   = (float*)(ws);               // reuse sa (dead after K4)

    const int M = S_LEN * BATCH;                // 131072
    dim3 blk(256);

    // K1: input-side gates, both directions
    gemm_nt<0><<<dim3(6, 2048), blk, 0, stream>>>(inp, w_ih_f, b_ih_f, xg_f, M, 384, 256);
    gemm_nt<0><<<dim3(6, 2048), blk, 0, stream>>>(inp, w_ih_b, b_ih_b, xg_b, M, 384, 256);

    // K2: sequential bidirectional GRU (128 independent WGs, 384 thr each)
    gru_scan<<<dim3(128), dim3(384), 0, stream>>>(
        xg_f, xg_b, w_hh_f, w_hh_b, b_hh_f, b_hh_b, hid0, outs, out + 16384);

    // K3: sent_annotation = out_state @ attn_w^T + attn_b
    gemm_nt<0><<<dim3(4, 2048), blk, 0, stream>>>(outs, attn_w, attn_b, sa, M, 256, 256);

    // K4: logits = sa @ comb_w^T, stored transposed (S,C,B)
    gemm_nt<1><<<dim3(4, 2048), blk, 0, stream>>>(sa, comb_w, nullptr, logits, M, 256, 256);

    // K5: softmax over batch + weighted partial sum over s-chunks
    attn_reduce<<<dim3(4, 64), blk, 0, stream>>>(logits, outs, part);

    // K6: final reduction over s-chunks -> sent
    reduce_part<<<dim3(64), blk, 0, stream>>>(part, out);
}

// Round 6
// 3348.698 us; speedup vs baseline: 1.3111x; 1.3111x over previous
//
#include <hip/hip_runtime.h>
#include <cstdint>
#include <cstddef>

#define S_LEN 2048
#define BATCH 64
#define ISZ   256
#define HSZ   128

// ---------------------------------------------------------------------------
// GEMM: C = A(MxK) @ W(NxK)^T (+bias)
// LAYOUT 0: C[m*N + n]   (row-major M x N)
// LAYOUT 1: C[(m/64)*N*64 + n*64 + (m%64)]   -> (s, c, b) transposed store
// ---------------------------------------------------------------------------
template<int LAYOUT>
__global__ __launch_bounds__(256)
void gemm_nt(const float* __restrict__ A, const float* __restrict__ W,
             const float* __restrict__ bias, float* __restrict__ C,
             int M, int N, int K)
{
    __shared__ float As[64][65];   // pad 65: A-reads 2-way conflict max
    __shared__ float Bs[64][68];   // pad 68: float4-aligned reads along n
    const int tid = threadIdx.x;
    const int tc = tid & 15, tr = tid >> 4;
    const int m0 = blockIdx.y * 64;
    const int n0 = blockIdx.x * 64;

    float acc[4][4] = {};

    for (int k0 = 0; k0 < K; k0 += 64) {
        // stage A tile (64 rows x 64 k), coalesced float4
        #pragma unroll
        for (int it = 0; it < 4; ++it) {
            int idx = tid + it * 256;
            int r = idx >> 4, c4 = (idx & 15) * 4;
            const float4 v = *reinterpret_cast<const float4*>(
                &A[(size_t)(m0 + r) * K + k0 + c4]);
            As[r][c4+0] = v.x; As[r][c4+1] = v.y;
            As[r][c4+2] = v.z; As[r][c4+3] = v.w;
        }
        // stage W tile transposed: Bs[k][n] = W[n0+n][k0+k]
        #pragma unroll
        for (int it = 0; it < 4; ++it) {
            int idx = tid + it * 256;
            int n = idx >> 4, k4 = (idx & 15) * 4;
            const float4 v = *reinterpret_cast<const float4*>(
                &W[(size_t)(n0 + n) * K + k0 + k4]);
            Bs[k4+0][n] = v.x; Bs[k4+1][n] = v.y;
            Bs[k4+2][n] = v.z; Bs[k4+3][n] = v.w;
        }
        __syncthreads();

        #pragma unroll
        for (int kk = 0; kk < 64; ++kk) {
            float a0 = As[tr*4+0][kk];
            float a1 = As[tr*4+1][kk];
            float a2 = As[tr*4+2][kk];
            float a3 = As[tr*4+3][kk];
            float4 b = *reinterpret_cast<const float4*>(&Bs[kk][tc*4]);
            acc[0][0] += a0*b.x; acc[0][1] += a0*b.y; acc[0][2] += a0*b.z; acc[0][3] += a0*b.w;
            acc[1][0] += a1*b.x; acc[1][1] += a1*b.y; acc[1][2] += a1*b.z; acc[1][3] += a1*b.w;
            acc[2][0] += a2*b.x; acc[2][1] += a2*b.y; acc[2][2] += a2*b.z; acc[2][3] += a2*b.w;
            acc[3][0] += a3*b.x; acc[3][1] += a3*b.y; acc[3][2] += a3*b.z; acc[3][3] += a3*b.w;
        }
        __syncthreads();
    }

    float bv[4];
    #pragma unroll
    for (int j = 0; j < 4; ++j)
        bv[j] = bias ? bias[n0 + tc*4 + j] : 0.f;

    #pragma unroll
    for (int i = 0; i < 4; ++i) {
        #pragma unroll
        for (int j = 0; j < 4; ++j) {
            float v = acc[i][j] + bv[j];
            int m = m0 + tr*4 + i;
            int n = n0 + tc*4 + j;
            if (LAYOUT == 0)
                C[(size_t)m * N + n] = v;
            else
                C[(size_t)(m >> 6) * ((size_t)N * 64) + (size_t)n * 64 + (m & 63)] = v;
        }
    }
}

// ---------------------------------------------------------------------------
// GRU recurrence: one WG per (direction, batch), 256 threads = 4 waves
// (1 per SIMD).  Residency recipe (r3/r4/r5 evidence): 4-wave WG +
// __launch_bounds__(256,1) is the ONLY config where the allocator goes
// >200 VGPRs; 6-wave WGs get their waves/EU request discarded (76 VGPRs,
// w[] in scratch, ~3100 cyc/step of L2 streaming).  Symmetric footprint:
// 192 weight words per thread, k-aligned per wave so the readlane
// broadcast stays wave-uniform:
//   thread j <128 (waves 0-1): r-row j (128 w) + n-row 256+j, k[0:64)
//   thread 128+j  (waves 2-3): z-row 128+j (128 w) + n-row 256+j, k[64:128)
// Each readlane h[k] feeds its main-row FMA and (in the owning half) the
// n-row FMA: 128 RL + 192 FMA per wave per step, zero LDS in the matvec.
// n-halves combine via LDS (gz/gnh); raw s_barrier + lgkmcnt(0) keeps the
// x(t+1) global prefetch in flight across barriers.
// ---------------------------------------------------------------------------
#define RL(v, l) __int_as_float(__builtin_amdgcn_readlane(__float_as_int(v), (l)))

__global__ __launch_bounds__(256, 1)
void gru_scan(const float* __restrict__ xg_f, const float* __restrict__ xg_b,
              const float* __restrict__ whh_f, const float* __restrict__ whh_b,
              const float* __restrict__ bhh_f, const float* __restrict__ bhh_b,
              const float* __restrict__ h0,     // (2,64,128)
              float* __restrict__ outs,         // (S,64,256)
              float* __restrict__ hid_out)      // (2,64,128)
{
    const int j    = threadIdx.x;        // 0..255
    const int lane = j & 63;
    const int dir  = blockIdx.x >> 6;
    const int b    = blockIdx.x & 63;
    const bool low = (j < 128);          // waves 0,1 (wave-uniform)
    const int jj   = j & 127;

    const float* xg  = dir ? xg_b  : xg_f;
    const float* whh = dir ? whh_b : whh_f;
    const float* bhh = dir ? bhh_b : bhh_f;

    // main row j: r-gate rows 0..127 (low) / z-gate rows 128..255 (high)
    float w[128];
    #pragma unroll
    for (int k4 = 0; k4 < 32; ++k4) {
        float4 v = *reinterpret_cast<const float4*>(&whh[(size_t)j * 128 + k4 * 4]);
        asm volatile("" : "+v"(v.x), "+v"(v.y), "+v"(v.z), "+v"(v.w));
        w[k4*4+0] = v.x; w[k4*4+1] = v.y; w[k4*4+2] = v.z; w[k4*4+3] = v.w;
    }
    // n-row 256+jj, own k-half: low -> k[0:64), high -> k[64:128)
    float wn[64];
    {
        const size_t nbase = (size_t)(256 + jj) * 128 + (low ? 0 : 64);
        #pragma unroll
        for (int k4 = 0; k4 < 16; ++k4) {
            float4 v = *reinterpret_cast<const float4*>(&whh[nbase + k4 * 4]);
            asm volatile("" : "+v"(v.x), "+v"(v.y), "+v"(v.z), "+v"(v.w));
            wn[k4*4+0] = v.x; wn[k4*4+1] = v.y; wn[k4*4+2] = v.z; wn[k4*4+3] = v.w;
        }
    }
    const float bh  = bhh[j];
    const float bhn = low ? bhh[256 + jj] : 0.f;

    __shared__ float hs[128];
    __shared__ float gz[128];    // z-gate dot (from high threads)
    __shared__ float gnh[128];   // n-gate high-half partial (from high threads)

    float hj = 0.f, xr = 0.f, xz = 0.f, xn = 0.f;
    if (low) {
        hj = h0[dir * (64*128) + b * 128 + j];
        hs[j] = hj;
        const int s0 = dir ? (S_LEN - 1) : 0;
        const float* xrow = xg + ((size_t)s0 * 64 + b) * 384;
        xr = xrow[j]; xz = xrow[j + 128]; xn = xrow[j + 256];
    }
    asm volatile("s_waitcnt lgkmcnt(0)" ::: "memory");
    __builtin_amdgcn_s_barrier();

    for (int t = 0; t < S_LEN; ++t) {
        // wave-local h copy (2 broadcast-free LDS reads per lane)
        const float hv0 = hs[lane];
        const float hv1 = hs[64 + lane];

        // x(t+1) prefetch: ~2 phases of slack before use, vmcnt never drained
        float pxr = 0.f, pxz = 0.f, pxn = 0.f;
        if (low && t + 1 < S_LEN) {
            const int s1 = dir ? (S_LEN - 2 - t) : (t + 1);
            const float* xrow = xg + ((size_t)s1 * 64 + b) * 384;
            pxr = xrow[j]; pxz = xrow[j + 128]; pxn = xrow[j + 256];
        }

        float a0 = 0.f, a1 = 0.f, a2 = 0.f, a3 = 0.f;  // main row
        float q0 = 0.f, q1 = 0.f;                      // n-row half
        if (low) {
            #pragma unroll
            for (int k = 0; k < 64; k += 4) {
                const float s0 = RL(hv0, k+0), s1 = RL(hv0, k+1);
                const float s2 = RL(hv0, k+2), s3 = RL(hv0, k+3);
                a0 = fmaf(w[k+0], s0, a0);  q0 = fmaf(wn[k+0], s0, q0);
                a1 = fmaf(w[k+1], s1, a1);  q1 = fmaf(wn[k+1], s1, q1);
                a2 = fmaf(w[k+2], s2, a2);  q0 = fmaf(wn[k+2], s2, q0);
                a3 = fmaf(w[k+3], s3, a3);  q1 = fmaf(wn[k+3], s3, q1);
            }
            #pragma unroll
            for (int k = 0; k < 64; k += 4) {
                const float s0 = RL(hv1, k+0), s1 = RL(hv1, k+1);
                const float s2 = RL(hv1, k+2), s3 = RL(hv1, k+3);
                a0 = fmaf(w[64+k+0], s0, a0);
                a1 = fmaf(w[64+k+1], s1, a1);
                a2 = fmaf(w[64+k+2], s2, a2);
                a3 = fmaf(w[64+k+3], s3, a3);
            }
        } else {
            #pragma unroll
            for (int k = 0; k < 64; k += 4) {
                const float s0 = RL(hv0, k+0), s1 = RL(hv0, k+1);
                const float s2 = RL(hv0, k+2), s3 = RL(hv0, k+3);
                a0 = fmaf(w[k+0], s0, a0);
                a1 = fmaf(w[k+1], s1, a1);
                a2 = fmaf(w[k+2], s2, a2);
                a3 = fmaf(w[k+3], s3, a3);
            }
            #pragma unroll
            for (int k = 0; k < 64; k += 4) {
                const float s0 = RL(hv1, k+0), s1 = RL(hv1, k+1);
                const float s2 = RL(hv1, k+2), s3 = RL(hv1, k+3);
                a0 = fmaf(w[64+k+0], s0, a0);  q0 = fmaf(wn[k+0], s0, q0);
                a1 = fmaf(w[64+k+1], s1, a1);  q1 = fmaf(wn[k+1], s1, q1);
                a2 = fmaf(w[64+k+2], s2, a2);  q0 = fmaf(wn[k+2], s2, q0);
                a3 = fmaf(w[64+k+3], s3, a3);  q1 = fmaf(wn[k+3], s3, q1);
            }
        }
        const float amain = (a0 + a1) + (a2 + a3) + bh;
        const float npart = q0 + q1;
        if (!low) {
            gz[jj]  = amain;        // z-dot (incl. bias)
            gnh[jj] = npart;        // n high-half partial
        }

        asm volatile("s_waitcnt lgkmcnt(0)" ::: "memory");
        __builtin_amdgcn_s_barrier();

        if (low) {
            const float hr = amain;
            const float hz = gz[j];
            const float hn = (npart + bhn) + gnh[j];
            const float r = 1.f / (1.f + __expf(-(xr + hr)));
            const float z = 1.f / (1.f + __expf(-(xz + hz)));
            const float x2 = xn + r * hn;
            const float ax = fabsf(x2);
            const float e  = __expf(-2.f * ax);
            const float nn = copysignf((1.f - e) / (1.f + e), x2);  // tanh
            const float hnew = nn + z * (hj - nn);   // (1-z)*n + z*h
            hj = hnew;
            hs[j] = hnew;
            const int s = dir ? (S_LEN - 1 - t) : t;
            outs[((size_t)s * 64 + b) * 256 + dir * 128 + j] = hnew;
            xr = pxr; xz = pxz; xn = pxn;
        }

        asm volatile("s_waitcnt lgkmcnt(0)" ::: "memory");
        __builtin_amdgcn_s_barrier();
    }

    if (low) hid_out[dir * (64*128) + b * 128 + j] = hj;
}

// ---------------------------------------------------------------------------
// Batch-axis softmax (over b, 64 lanes = one wave) + weighted partial
// reduction over a 32-step s-chunk.  logits are in (S, C, B) layout.
// ---------------------------------------------------------------------------
__global__ __launch_bounds__(256)
void attn_reduce(const float* __restrict__ lt,    // (S,256,64)
                 const float* __restrict__ outs,  // (S,64,256)
                 float* __restrict__ part)        // (64 chunks,64 b,256 c)
{
    __shared__ float ltile[64 * 64];     // [c_local][b]
    __shared__ float otile[64 * 65];     // [b][c_local] padded

    const int tid  = threadIdx.x;
    const int lane = tid & 63;           // = b
    const int wv   = tid >> 6;           // wave 0..3
    const int c0   = blockIdx.x * 64;    // channel block
    const int sc   = blockIdx.y;         // s-chunk 0..63

    float acc[16];
    #pragma unroll
    for (int i = 0; i < 16; ++i) acc[i] = 0.f;

    for (int si = 0; si < 32; ++si) {
        const int s = sc * 32 + si;

        // logits tile: 4096 contiguous floats
        const float4* src = reinterpret_cast<const float4*>(
            lt + (size_t)s * 16384 + (size_t)c0 * 64);
        #pragma unroll
        for (int i = 0; i < 4; ++i)
            reinterpret_cast<float4*>(ltile)[tid + i * 256] = src[tid + i * 256];

        // out_state tile (64 b x 64 c), coalesced along c
        #pragma unroll
        for (int i = 0; i < 4; ++i) {
            int idx = tid + i * 256;
            int bb = idx >> 4, c4 = (idx & 15) * 4;
            float4 v = *reinterpret_cast<const float4*>(
                &outs[((size_t)s * 64 + bb) * 256 + c0 + c4]);
            otile[bb*65 + c4+0] = v.x; otile[bb*65 + c4+1] = v.y;
            otile[bb*65 + c4+2] = v.z; otile[bb*65 + c4+3] = v.w;
        }
        __syncthreads();

        #pragma unroll
        for (int ci = 0; ci < 16; ++ci) {
            int c = wv * 16 + ci;
            float x = ltile[c * 64 + lane];
            float m = x;
            #pragma unroll
            for (int off = 32; off; off >>= 1)
                m = fmaxf(m, __shfl_xor(m, off));
            float e = __expf(x - m);
            float ssum = e;
            #pragma unroll
            for (int off = 32; off; off >>= 1)
                ssum += __shfl_xor(ssum, off);
            float attn = e / ssum;
            acc[ci] += attn * otile[lane * 65 + c];
        }
        __syncthreads();
    }

    #pragma unroll
    for (int ci = 0; ci < 16; ++ci) {
        int c = wv * 16 + ci;
        part[(size_t)sc * 16384 + (size_t)lane * 256 + c0 + c] = acc[ci];
    }
}

__global__ __launch_bounds__(256)
void reduce_part(const float* __restrict__ part, float* __restrict__ sent)
{
    int idx = blockIdx.x * 256 + threadIdx.x;   // 0..16383 = b*256+c
    float s = 0.f;
    for (int sc = 0; sc < 64; ++sc)
        s += part[(size_t)sc * 16384 + idx];
    sent[idx] = s;
}

// ---------------------------------------------------------------------------
extern "C" void kernel_launch(void* const* d_in, const int* in_sizes, int n_in,
                              void* d_out, int out_size, void* d_ws, size_t ws_size,
                              hipStream_t stream)
{
    const float* inp    = (const float*)d_in[0];
    const float* hid0   = (const float*)d_in[1];
    const float* w_ih_f = (const float*)d_in[2];
    const float* w_hh_f = (const float*)d_in[3];
    const float* b_ih_f = (const float*)d_in[4];
    const float* b_hh_f = (const float*)d_in[5];
    const float* w_ih_b = (const float*)d_in[6];
    const float* w_hh_b = (const float*)d_in[7];
    const float* b_ih_b = (const float*)d_in[8];
    const float* b_hh_b = (const float*)d_in[9];
    const float* attn_w = (const float*)d_in[10];
    const float* attn_b = (const float*)d_in[11];
    const float* comb_w = (const float*)d_in[12];

    float* out = (float*)d_out;   // [0,16384): sent, [16384,32768): hid_out

    char* ws = (char*)d_ws;
    const size_t XG_BYTES = (size_t)S_LEN * BATCH * 384 * 4;  // 201,326,592
    const size_t OS_BYTES = (size_t)S_LEN * BATCH * 256 * 4;  // 134,217,728
    if (ws_size < 2 * XG_BYTES + OS_BYTES) return;  // need 512 MiB scratch

    float* xg_f   = (float*)(ws);
    float* xg_b   = (float*)(ws + XG_BYTES);
    float* outs   = (float*)(ws + 2 * XG_BYTES);
    float* sa     = (float*)(ws);               // reuse xg_f (dead after scan)
    float* logits = (float*)(ws + XG_BYTES);    // reuse xg_b
    float* part   = (float*)(ws);               // reuse sa (dead after K4)

    const int M = S_LEN * BATCH;                // 131072
    dim3 blk(256);

    // K1: input-side gates, both directions
    gemm_nt<0><<<dim3(6, 2048), blk, 0, stream>>>(inp, w_ih_f, b_ih_f, xg_f, M, 384, 256);
    gemm_nt<0><<<dim3(6, 2048), blk, 0, stream>>>(inp, w_ih_b, b_ih_b, xg_b, M, 384, 256);

    // K2: sequential bidirectional GRU (128 independent WGs, 256 thr each)
    gru_scan<<<dim3(128), dim3(256), 0, stream>>>(
        xg_f, xg_b, w_hh_f, w_hh_b, b_hh_f, b_hh_b, hid0, outs, out + 16384);

    // K3: sent_annotation = out_state @ attn_w^T + attn_b
    gemm_nt<0><<<dim3(4, 2048), blk, 0, stream>>>(outs, attn_w, attn_b, sa, M, 256, 256);

    // K4: logits = sa @ comb_w^T, stored transposed (S,C,B)
    gemm_nt<1><<<dim3(4, 2048), blk, 0, stream>>>(sa, comb_w, nullptr, logits, M, 256, 256);

    // K5: softmax over batch + weighted partial sum over s-chunks
    attn_reduce<<<dim3(4, 64), blk, 0, stream>>>(logits, outs, part);

    // K6: final reduction over s-chunks -> sent
    reduce_part<<<dim3(64), blk, 0, stream>>>(part, out);
}